// Round 9
// baseline (218.865 us; speedup 1.0000x reference)
//
#include <hip/hip_runtime.h>
#include <hip/hip_bf16.h>
#include <cstdint>

#define D_IN  4096
#define D_OUT 4096

typedef __attribute__((ext_vector_type(4)))  int   i32x4;

typedef const __attribute__((address_space(1))) unsigned g_u32;
typedef __attribute__((address_space(3))) unsigned       l_u32;

// ------- pass 1 (fused): blocks [0,1024) per-block max|W| -> atomicMax;
//         blocks [1024, ...) quantize x to int8 ------------------------------
__global__ void prep_kernel(const float* __restrict__ W, int nw,
                            const float* __restrict__ x,
                            char* __restrict__ xq,
                            const float* __restrict__ xscale, int nx,
                            unsigned* __restrict__ wsp) {
    int tid = threadIdx.x;
    if (blockIdx.x < 1024) {
        __shared__ float red[256];
        float m = 0.f;
        for (int i = (blockIdx.x * 256 + tid) * 4; i < nw; i += 1024 * 256 * 4) {
            float4 v = *(const float4*)(W + i);
            m = fmaxf(m, fmaxf(fmaxf(fabsf(v.x), fabsf(v.y)),
                               fmaxf(fabsf(v.z), fabsf(v.w))));
        }
        red[tid] = m; __syncthreads();
        for (int s = 128; s > 0; s >>= 1) {
            if (tid < s) red[tid] = fmaxf(red[tid], red[tid + s]);
            __syncthreads();
        }
        if (tid == 0) atomicMax(wsp, __float_as_uint(red[0]));
    } else {
        int i = ((blockIdx.x - 1024) * 256 + tid) * 4;
        if (i >= nx) return;
        float inv = 127.0f / fmaxf(xscale[0], 1e-8f);
        float4 v = *(const float4*)(x + i);
        char4 o;
        o.x = (char)fminf(fmaxf(rintf(v.x * inv), -127.f), 127.f);
        o.y = (char)fminf(fmaxf(rintf(v.y * inv), -127.f), 127.f);
        o.z = (char)fminf(fmaxf(rintf(v.z * inv), -127.f), 127.f);
        o.w = (char)fminf(fmaxf(rintf(v.w * inv), -127.f), 127.f);
        *(char4*)(xq + i) = o;
    }
}

// ------- pass 2: W (K x N) -> int8 transposed Wt (N x K), vectorized --------
__global__ void convW_kernel(const float* __restrict__ W,
                             char* __restrict__ Wt,
                             const unsigned* __restrict__ wsp) {
    __shared__ float tile[64][65];
    const float wmax = __uint_as_float(wsp[0]);
    const float inv  = 127.0f / wmax;
    const int n0 = blockIdx.x * 64, k0 = blockIdx.y * 64;
    const int t = threadIdx.x;
    {
        const int r = t >> 2, c0 = (t & 3) * 16;
        const float* src = W + (size_t)(k0 + r) * D_OUT + n0 + c0;
#pragma unroll
        for (int j = 0; j < 4; ++j) {
            float4 v = *(const float4*)(src + j * 4);
            tile[r][c0 + j * 4 + 0] = v.x;
            tile[r][c0 + j * 4 + 1] = v.y;
            tile[r][c0 + j * 4 + 2] = v.z;
            tile[r][c0 + j * 4 + 3] = v.w;
        }
    }
    __syncthreads();
    {
        const int n = t >> 2, kc = (t & 3) * 16;
        int4 pk;
        int* pw = (int*)&pk;
#pragma unroll
        for (int w = 0; w < 4; ++w) {
            unsigned word = 0;
#pragma unroll
            for (int j = 0; j < 4; ++j) {
                int q = (int)rintf(tile[kc + w * 4 + j][n] * inv);
                word |= ((unsigned)(unsigned char)(char)q) << (8 * j);
            }
            pw[w] = (int)word;
        }
        *(int4*)(Wt + (size_t)(n0 + n) * D_IN + k0 + kc) = pk;
    }
}

// ------- pass 3: 256x128 int8 GEMM, BK=64, 2 blocks/CU (occupancy probe) ---
// A:[M][K] i8, Bt:[N][K] i8, C = i32acc * (sx*ws) + bias.
// Tile 256M x 128N, 8 waves of 64x64 out -> acc 64 regs; LDS 48 KB/block
// (A 16K + B 8K, dbuf) -> with launch_bounds(512,4): 2 blocks/CU resident,
// so block B computes through block A's barrier/vmcnt drain (m114 overlap).
// Schedule = proven 2-region: R1 {bar; 8 ds_read; 16 MFMA}; R2 {bar;
// STAGE(t+2)->cur (3 loads); vmcnt(3)} -> t+1 resident at next R1.
// Swizzle (64B rows): involution sw = p ^ ((p>>7)&3)<<4 on SOURCE; reads use
// chunk = (lane>>4) ^ ((lane>>1)&3): per quarter-wave 8 slots x 2 = free.
__global__ __launch_bounds__(512, 4)
void gemm_kernel(const char* __restrict__ A,
                 const char* __restrict__ Bt,
                 const float* __restrict__ bias,
                 const float* __restrict__ xscale,
                 const unsigned* __restrict__ wsp,
                 float* __restrict__ C, int M) {
    constexpr int K = D_IN, N = D_OUT;
    constexpr int NT = K / 64;                 // 64 K-tiles of 64 B
    __shared__ char lds[2 * 24576];            // buf: A 16K @0, B 8K @16384

    const int tid  = threadIdx.x;
    const int lane = tid & 63;
    const int wid  = tid >> 6;
    const int wr   = wid >> 1;                 // 0..3  (M)
    const int wc   = wid & 1;                  // 0..1  (N)

    // bijective XCD-aware block swizzle
    const int nTn = N / 128;                   // 32
    const int nwg = gridDim.x;                 // 1024
    int bid = blockIdx.x;
    int q8 = nwg >> 3, r8 = nwg & 7;
    int xcd = bid & 7, idx = bid >> 3;
    int swz = (xcd < r8 ? xcd * (q8 + 1) : r8 * (q8 + 1) + (xcd - r8) * q8) + idx;
    const int tm = swz / nTn, tn = swz % nTn;
    const int row0 = tm * 256, col0 = tn * 128;

    // staging offsets: LDS dest LINEAR; XOR involution on SOURCE
    // sw = p ^ ((p>>7)&3)<<4  (chunk bits [5:4] ^= row bits [2:1])
    int srcA0, srcA1, srcB0;
    {
        int p0 = tid * 16;                     // A chunk 0: [0, 8192)
        int p1 = (512 + tid) * 16;             // A chunk 1: [8192, 16384)
        int s0 = p0 ^ (((p0 >> 7) & 3) << 4);
        int s1 = p1 ^ (((p1 >> 7) & 3) << 4);
        srcA0 = (s0 >> 6) * K + (s0 & 63);
        srcA1 = (s1 >> 6) * K + (s1 & 63);
        srcB0 = srcA0;                         // B uses p = tid*16 too
    }
    const int dstA0 = tid * 16, dstA1 = (512 + tid) * 16, dstB0 = 16384 + tid * 16;

    const char* srcA = A  + (size_t)row0 * K;
    const char* srcB = Bt + (size_t)col0 * K;
    char* b0 = lds;
    char* b1 = lds + 24576;

    auto STAGE = [&](int t, char* buf) {       // 3 loads: A 16K + B 8K
        __builtin_amdgcn_global_load_lds((g_u32*)(srcA + t * 64 + srcA0),
                                         (l_u32*)(buf + dstA0), 16, 0, 0);
        __builtin_amdgcn_global_load_lds((g_u32*)(srcA + t * 64 + srcA1),
                                         (l_u32*)(buf + dstA1), 16, 0, 0);
        __builtin_amdgcn_global_load_lds((g_u32*)(srcB + t * 64 + srcB0),
                                         (l_u32*)(buf + dstB0), 16, 0, 0);
    };

    // ---- prologue ----
    STAGE(0, b0);
    STAGE(1, b1);

    i32x4 acc[4][4];
#pragma unroll
    for (int m = 0; m < 4; ++m)
#pragma unroll
        for (int n = 0; n < 4; ++n) acc[m][n] = (i32x4){0, 0, 0, 0};

    // read addressing: chunk = (lane>>4) ^ ((lane>>1)&3), 16B units
    const int cOff  = (((lane >> 4) ^ ((lane >> 1) & 3)) << 4);
    const int aBase = (wr * 64 + (lane & 15)) * 64 + cOff;
    const int bBase = 16384 + (wc * 64 + (lane & 15)) * 64 + cOff;

    asm volatile("s_waitcnt vmcnt(3)" ::: "memory");   // tile0 resident

    auto KTILE = [&](int t, char* cur) {
        i32x4 a[4], b[4];
        // ================= R1: compute =================
        __builtin_amdgcn_s_barrier();
#pragma unroll
        for (int n = 0; n < 4; ++n) b[n] = *(const i32x4*)(cur + bBase + n * 1024);
#pragma unroll
        for (int m = 0; m < 4; ++m) a[m] = *(const i32x4*)(cur + aBase + m * 1024);
        __builtin_amdgcn_s_setprio(1);
#pragma unroll
        for (int m = 0; m < 4; ++m)
#pragma unroll
            for (int n = 0; n < 4; ++n)
                acc[m][n] = __builtin_amdgcn_mfma_i32_16x16x64_i8(a[m], b[n], acc[m][n], 0, 0, 0);
        __builtin_amdgcn_s_setprio(0);

        // ================= R2: publish =================
        __builtin_amdgcn_s_barrier();
        if (t + 2 < NT) {
            STAGE(t + 2, cur);
            asm volatile("s_waitcnt vmcnt(3)" ::: "memory");   // t+1 resident
        } else {
            asm volatile("s_waitcnt vmcnt(0)" ::: "memory");
        }
    };

    for (int t = 0; t < NT; t += 2) {
        KTILE(t,     b0);
        KTILE(t + 1, b1);
    }

    // ---- epilogue: C = acc * (sx*ws) + bias ----
    const float wmax  = __uint_as_float(wsp[0]);
    const float scale = (fmaxf(xscale[0], 1e-8f) * (1.0f / 127.0f)) * (wmax * (1.0f / 127.0f));
    const int lr = (lane >> 4) * 4, lc = lane & 15;
#pragma unroll
    for (int n = 0; n < 4; ++n) {
        int col = col0 + wc * 64 + n * 16 + lc;
        float bv = bias[col];
#pragma unroll
        for (int m = 0; m < 4; ++m) {
            int rowb = row0 + wr * 64 + m * 16 + lr;
            i32x4 v = acc[m][n];
#pragma unroll
            for (int r2 = 0; r2 < 4; ++r2)
                C[(size_t)(rowb + r2) * N + col] = (float)v[r2] * scale + bv;
        }
    }
}

extern "C" void kernel_launch(void* const* d_in, const int* in_sizes, int n_in,
                              void* d_out, int out_size, void* d_ws, size_t ws_size,
                              hipStream_t stream) {
    const float* x      = (const float*)d_in[0];   // [4,2048,4096] f32
    const float* W      = (const float*)d_in[1];   // [4096,4096] f32
    const float* xscale = (const float*)d_in[2];   // scalar
    const float* bias   = (const float*)d_in[3];   // [4096] f32
    float* out = (float*)d_out;

    const int nx = in_sizes[0];            // 33554432
    const int nw = in_sizes[1];            // 16777216
    const int M  = nx / D_IN;              // 8192

    char*     xq  = (char*)d_ws;                               // 32 MiB
    char*     Wt  = (char*)d_ws + (size_t)nx;                  // 16 MiB
    unsigned* wsp = (unsigned*)((char*)d_ws + (size_t)nx + nw);// 4 B

    hipMemsetAsync(wsp, 0, 4, stream);

    int qblocks = nx / 4 / 256;            // 32768
    prep_kernel<<<1024 + qblocks, 256, 0, stream>>>(W, nw, x, xq, xscale, nx, wsp);

    dim3 tb(256);
    dim3 tg(D_OUT / 64, D_IN / 64);        // 64 x 64
    convW_kernel<<<tg, tb, 0, stream>>>(W, Wt, wsp);

    int grid = (M / 256) * (D_OUT / 128);  // 1024
    gemm_kernel<<<grid, 512, 0, stream>>>(xq, Wt, bias, xscale, wsp, out, M);
}